// Round 6
// baseline (117.329 us; speedup 1.0000x reference)
//
#include <hip/hip_runtime.h>

namespace {

constexpr int IMG = 512;
constexpr int S = 8;                    // output rows per wave
constexpr int NSTRIPS = IMG / S;        // 64
constexpr int NWAVES = 32 * NSTRIPS;    // 2048
constexpr int NBLK = NWAVES / 4;        // 512 blocks of 4 waves
constexpr float THR = 50.0f / 255.0f;

// Final loss is linear in the 5 raw sums; pre-weight per block.
constexpr double N_PIX = 32.0 * 512.0 * 512.0;
constexpr double N_L1  = 32.0 * 256.0 * 256.0;
constexpr double N_L2  = 32.0 * 128.0 * 128.0;
constexpr double N_L3  = 32.0 * 64.0 * 64.0;
constexpr double C_REC = 1.0 / N_PIX;
constexpr double C_REG = 2.0 / N_PIX;
constexpr double C_W1  = 0.05 / (9.0 * N_L1);
constexpr double C_W2  = 0.05 / (6.0 * N_L2);
constexpr double C_W3  = 0.05 / (3.0 * N_L3);

struct F4 { float v[4]; };
struct F8 { float v[8]; };
struct Row { F8 g; float gl, gr; };     // 8 cols + pre-shuffled zero-pad halos

// Horizontal resize blend: 4 phase values (cols j=4L..4L+3) -> 8 upsampled cols.
// jax.image.resize 'linear' 256->512: even g=2j: 0.25*in[j-1]+0.75*in[j];
// odd g=2j+1: 0.75*in[j]+0.25*in[j+1]; index-clamped (bit-exact R1-R5).
__device__ __forceinline__ F8 hblend(const F4& p, int lane) {
  float left  = __shfl_up(p.v[3], 1);
  float right = __shfl_down(p.v[0], 1);
  if (lane == 0)  left  = p.v[0];
  if (lane == 63) right = p.v[3];
  F8 h;
  h.v[0] = 0.25f*left   + 0.75f*p.v[0];
  h.v[1] = 0.75f*p.v[0] + 0.25f*p.v[1];
  h.v[2] = 0.25f*p.v[0] + 0.75f*p.v[1];
  h.v[3] = 0.75f*p.v[1] + 0.25f*p.v[2];
  h.v[4] = 0.25f*p.v[1] + 0.75f*p.v[2];
  h.v[5] = 0.75f*p.v[2] + 0.25f*p.v[3];
  h.v[6] = 0.25f*p.v[2] + 0.75f*p.v[3];
  h.v[7] = 0.75f*p.v[3] + 0.25f*right;
  return h;
}

// Vertical resize blend -> one g1 row, with conv zero-pad halos pre-shuffled.
__device__ __forceinline__ Row vblend(const F8& a, const F8& b, float wa, float wb, int lane) {
  Row r;
#pragma unroll
  for (int c = 0; c < 8; ++c) r.g.v[c] = wa*a.v[c] + wb*b.v[c];
  const float gl = __shfl_up(r.g.v[7], 1);
  const float gr = __shfl_down(r.g.v[0], 1);
  r.gl = (lane == 0)  ? 0.0f : gl;
  r.gr = (lane == 63) ? 0.0f : gr;
  return r;
}

__device__ __forceinline__ void conv_acc(const Row& r, const float* wk3, F8& acc) {
#pragma unroll
  for (int c = 0; c < 8; ++c) {
    const float gm1 = (c == 0) ? r.gl : r.g.v[c-1];
    const float gp1 = (c == 7) ? r.gr : r.g.v[c+1];
    acc.v[c] += wk3[0]*gm1 + wk3[1]*r.g.v[c] + wk3[2]*gp1;
  }
}

__device__ __forceinline__ F8 conv3(const Row& r0, const Row& r1, const Row& r2,
                                    const float* wk) {
  F8 o;
#pragma unroll
  for (int c = 0; c < 8; ++c) o.v[c] = 0.0f;
  conv_acc(r0, wk + 0, o);
  conv_acc(r1, wk + 3, o);
  conv_acc(r2, wk + 6, o);
#pragma unroll
  for (int c = 0; c < 8; ++c) o.v[c] = fminf(fmaxf(o.v[c], 0.0f), 1.0f);
  return o;
}

__device__ __forceinline__ F4 haarL1(const F8& e, const F8& o, float thr, float& acc) {
  F4 ll;
#pragma unroll
  for (int c = 0; c < 4; ++c) {
    const float a = e.v[2*c], b = e.v[2*c+1], cc = o.v[2*c], d = o.v[2*c+1];
    ll.v[c] = (a + b + cc + d) * 0.5f;
    const float lh = (a - b + cc - d) * 0.5f;
    const float hl = (a + b - cc - d) * 0.5f;
    const float hh = (a - b - cc + d) * 0.5f;
    acc += fminf(fabsf(lh), thr) + fminf(fabsf(hl), thr) + fminf(fabsf(hh), thr);
  }
  return ll;
}

__device__ __forceinline__ float haar1pair(float a, float b, float cc, float d,
                                           float thr, float& acc) {
  const float lh = (a - b + cc - d) * 0.5f;
  const float hl = (a + b - cc - d) * 0.5f;
  const float hh = (a - b - cc + d) * 0.5f;
  acc += fminf(fabsf(lh), thr) + fminf(fabsf(hl), thr) + fminf(fabsf(hh), thr);
  return (a + b + cc + d) * 0.5f;
}

__global__ __launch_bounds__(256, 2) void n2n_wavelet_kernel(
    const float* __restrict__ noisy,
    const float* __restrict__ weight,
    unsigned int* __restrict__ counter,   // d_ws[0..7], zeroed by memset node
    double* __restrict__ partial,         // d_ws + 8, NBLK doubles
    float* __restrict__ out) {
  const int t = threadIdx.x;
  const int lane = t & 63;
  const int gwid = blockIdx.x * 4 + (t >> 6);
  const int strip = gwid & (NSTRIPS - 1);
  const int b = gwid >> 6;
  const float* base = noisy + (size_t)b * IMG * IMG + lane * 8;

  const int y0 = strip * S;
  const int k0 = y0 >> 1;                 // phase-row index of first pair
  const bool lastStrip = (y0 == IMG - S);

  // ---- Hoist ALL 24 dwordx4 loads: phase rows k0-1 .. k0+4 (clamped) ----
  float4 le0[6], le1[6], lo0[6], lo1[6];
#pragma unroll
  for (int i = 0; i < 6; ++i) {
    int r = k0 - 1 + i;
    r = r < 0 ? 0 : (r > 255 ? 255 : r);
    const float* pe = base + (2 * r) * IMG;       // even image row (p0 phase)
    const float* po = base + (2 * r + 1) * IMG;   // odd image row (p3 phase)
    le0[i] = *(const float4*)pe;
    le1[i] = *(const float4*)(pe + 4);
    lo0[i] = *(const float4*)po;
    lo1[i] = *(const float4*)(po + 4);
  }

  float wk[9];
#pragma unroll
  for (int i = 0; i < 9; ++i) wk[i] = weight[i];

  // ---- Extract checkerboard phases + horizontal blends (consume in order) ----
  F8 h0[6], h3[6];
#pragma unroll
  for (int i = 0; i < 6; ++i) {
    F4 e, o;
    e.v[0] = le0[i].x; e.v[1] = le0[i].z; e.v[2] = le1[i].x; e.v[3] = le1[i].z;
    o.v[0] = lo0[i].y; o.v[1] = lo0[i].w; o.v[2] = lo1[i].y; o.v[3] = lo1[i].w;
    h0[i] = hblend(e, lane);
    h3[i] = hblend(o, lane);
  }

  float rec = 0.f, rgg = 0.f, w1a = 0.f, w2a = 0.f, w3a = 0.f;
  const float thr1 = THR * 0.25f, thr2 = THR * 0.5f;

  // ---- g1 prologue rows y0-1 (odd), y0 (even) ----
  Row g1m, g1c;
  if (y0 == 0) {                                  // SAME conv zero-pad row -1
#pragma unroll
    for (int c = 0; c < 8; ++c) g1m.g.v[c] = 0.f;
    g1m.gl = 0.f; g1m.gr = 0.f;
  } else {
    g1m = vblend(h0[0], h0[1], 0.75f, 0.25f, lane);
  }
  g1c = vblend(h0[0], h0[1], 0.25f, 0.75f, lane);

  F4 ll1Prev;
  float ll2Prev0 = 0.f, ll2Prev1 = 0.f;

#pragma unroll
  for (int p = 0; p < 4; ++p) {
    const Row g1p = vblend(h0[p + 1], h0[p + 2], 0.75f, 0.25f, lane);  // g1[2k+1]

    // out row 2k (even)
    const F8 outE = conv3(g1m, g1c, g1p, wk);
#pragma unroll
    for (int c = 0; c < 8; ++c) {
      const float g2 = 0.25f * h3[p].v[c] + 0.75f * h3[p + 1].v[c];
      float d = outE.v[c] - g2;        rec += d*d;
      d = outE.v[c] - g1c.g.v[c];      rgg += d*d;
    }

    Row g1q = vblend(h0[p + 1], h0[p + 2], 0.25f, 0.75f, lane);        // g1[2k+2]
    if (lastStrip && p == 3) {                                         // g1[512]=0
#pragma unroll
      for (int c = 0; c < 8; ++c) g1q.g.v[c] = 0.f;
      g1q.gl = 0.f; g1q.gr = 0.f;
    }

    // out row 2k+1 (odd)
    const F8 outO = conv3(g1c, g1p, g1q, wk);
#pragma unroll
    for (int c = 0; c < 8; ++c) {
      const float g2 = 0.75f * h3[p + 1].v[c] + 0.25f * h3[p + 2].v[c];
      float d = outO.v[c] - g2;        rec += d*d;
      d = outO.v[c] - g1p.g.v[c];      rgg += d*d;
    }

    // Haar level 1 (rows 2k,2k+1; col pairs lane-local)
    const F4 ll1 = haarL1(outE, outO, thr1, w1a);
    if ((p & 1) == 0) {
      ll1Prev = ll1;
    } else {
      const float ll20 = haar1pair(ll1Prev.v[0], ll1Prev.v[1], ll1.v[0], ll1.v[1], thr2, w2a);
      const float ll21 = haar1pair(ll1Prev.v[2], ll1Prev.v[3], ll1.v[2], ll1.v[3], thr2, w2a);
      if (p == 1) {
        ll2Prev0 = ll20; ll2Prev1 = ll21;
      } else {
        const float lh = (ll2Prev0 - ll2Prev1 + ll20 - ll21) * 0.5f;
        const float hl = (ll2Prev0 + ll2Prev1 - ll20 - ll21) * 0.5f;
        const float hh = (ll2Prev0 - ll2Prev1 - ll20 + ll21) * 0.5f;
        w3a += fminf(fabsf(lh), THR) + fminf(fabsf(hl), THR) + fminf(fabsf(hh), THR);
      }
    }

    g1m = g1p; g1c = g1q;
  }

  // ---- Wave reduce 5 sums -> LDS -> block contribution ----
  float vals[5] = {rec, rgg, w1a, w2a, w3a};
#pragma unroll
  for (int v = 0; v < 5; ++v) {
#pragma unroll
    for (int off = 32; off > 0; off >>= 1) vals[v] += __shfl_down(vals[v], off);
  }
  __shared__ float sRed[4][5];
  __shared__ int lastFlag;
  const int wave = t >> 6;
  if (lane == 0) {
#pragma unroll
    for (int v = 0; v < 5; ++v) sRed[wave][v] = vals[v];
  }
  __syncthreads();

  if (t == 0) {
    double s[5];
#pragma unroll
    for (int v = 0; v < 5; ++v)
      s[v] = (double)(sRed[0][v] + sRed[1][v] + sRed[2][v] + sRed[3][v]);
    const double contrib =
        C_REC*s[0] + C_REG*s[1] + C_W1*s[2] + C_W2*s[3] + C_W3*s[4];
    // Agent-scope release store: visible across XCDs (G16) before counter bump.
    __hip_atomic_store(&partial[blockIdx.x], contrib,
                       __ATOMIC_RELEASE, __HIP_MEMORY_SCOPE_AGENT);
    const unsigned int old = __hip_atomic_fetch_add(
        counter, 1u, __ATOMIC_ACQ_REL, __HIP_MEMORY_SCOPE_AGENT);
    lastFlag = (old == (unsigned int)(NBLK - 1));
  }
  __syncthreads();

  // ---- Last block performs the final reduction (wave 0 only) ----
  if (lastFlag && t < 64) {
    double s = 0.0;
#pragma unroll
    for (int i = 0; i < NBLK / 64; ++i)
      s += __hip_atomic_load(&partial[i * 64 + t],
                             __ATOMIC_RELAXED, __HIP_MEMORY_SCOPE_AGENT);
#pragma unroll
    for (int off = 32; off > 0; off >>= 1) s += __shfl_down(s, off);
    if (t == 0) out[0] = (float)s;
  }
}

}  // namespace

extern "C" void kernel_launch(void* const* d_in, const int* in_sizes, int n_in,
                              void* d_out, int out_size, void* d_ws, size_t ws_size,
                              hipStream_t stream) {
  const float* noisy  = (const float*)d_in[0];
  const float* weight = (const float*)d_in[1];
  unsigned int* counter = (unsigned int*)d_ws;        // 8 bytes
  double* partial = (double*)((char*)d_ws + 8);       // NBLK doubles
  float* out = (float*)d_out;

  hipMemsetAsync(d_ws, 0, 8, stream);                 // zero the counter (graph-capturable)
  hipLaunchKernelGGL(n2n_wavelet_kernel, dim3(NBLK), dim3(256), 0, stream,
                     noisy, weight, counter, partial, out);
}

// Round 7
// 84.680 us; speedup vs baseline: 1.3856x; 1.3856x over previous
//
#include <hip/hip_runtime.h>

namespace {

constexpr int IMG = 512;
constexpr int S = 8;                    // output rows per wave
constexpr int NSTRIPS = IMG / S;        // 64
constexpr int NWAVES = 32 * NSTRIPS;    // 2048
constexpr int NBLK = NWAVES / 4;        // 512 blocks of 4 waves
constexpr float THR = 50.0f / 255.0f;

// Final loss is linear in the 5 raw sums; pre-weight per wave.
constexpr double N_PIX = 32.0 * 512.0 * 512.0;
constexpr double N_L1  = 32.0 * 256.0 * 256.0;
constexpr double N_L2  = 32.0 * 128.0 * 128.0;
constexpr double N_L3  = 32.0 * 64.0 * 64.0;
constexpr double C_REC = 1.0 / N_PIX;
constexpr double C_REG = 2.0 / N_PIX;
constexpr double C_W1  = 0.05 / (9.0 * N_L1);
constexpr double C_W2  = 0.05 / (6.0 * N_L2);
constexpr double C_W3  = 0.05 / (3.0 * N_L3);

struct F4 { float v[4]; };
struct F8 { float v[8]; };
struct Row { F8 g; float gl, gr; };     // 8 cols + pre-shuffled zero-pad halos

// Horizontal resize blend: 4 phase values (cols j=4L..4L+3) -> 8 upsampled cols.
// jax.image.resize 'linear' 256->512: even g=2j: 0.25*in[j-1]+0.75*in[j];
// odd g=2j+1: 0.75*in[j]+0.25*in[j+1]; index-clamped (bit-exact R1-R5).
__device__ __forceinline__ F8 hblend(const F4& p, int lane) {
  float left  = __shfl_up(p.v[3], 1);
  float right = __shfl_down(p.v[0], 1);
  if (lane == 0)  left  = p.v[0];
  if (lane == 63) right = p.v[3];
  F8 h;
  h.v[0] = 0.25f*left   + 0.75f*p.v[0];
  h.v[1] = 0.75f*p.v[0] + 0.25f*p.v[1];
  h.v[2] = 0.25f*p.v[0] + 0.75f*p.v[1];
  h.v[3] = 0.75f*p.v[1] + 0.25f*p.v[2];
  h.v[4] = 0.25f*p.v[1] + 0.75f*p.v[2];
  h.v[5] = 0.75f*p.v[2] + 0.25f*p.v[3];
  h.v[6] = 0.25f*p.v[2] + 0.75f*p.v[3];
  h.v[7] = 0.75f*p.v[3] + 0.25f*right;
  return h;
}

// Vertical resize blend -> one g1 row, with conv zero-pad halos pre-shuffled.
__device__ __forceinline__ Row vblend(const F8& a, const F8& b, float wa, float wb, int lane) {
  Row r;
#pragma unroll
  for (int c = 0; c < 8; ++c) r.g.v[c] = wa*a.v[c] + wb*b.v[c];
  const float gl = __shfl_up(r.g.v[7], 1);
  const float gr = __shfl_down(r.g.v[0], 1);
  r.gl = (lane == 0)  ? 0.0f : gl;
  r.gr = (lane == 63) ? 0.0f : gr;
  return r;
}

__device__ __forceinline__ void conv_acc(const Row& r, const float* wk3, F8& acc) {
#pragma unroll
  for (int c = 0; c < 8; ++c) {
    const float gm1 = (c == 0) ? r.gl : r.g.v[c-1];
    const float gp1 = (c == 7) ? r.gr : r.g.v[c+1];
    acc.v[c] += wk3[0]*gm1 + wk3[1]*r.g.v[c] + wk3[2]*gp1;
  }
}

__device__ __forceinline__ F8 conv3(const Row& r0, const Row& r1, const Row& r2,
                                    const float* wk) {
  F8 o;
#pragma unroll
  for (int c = 0; c < 8; ++c) o.v[c] = 0.0f;
  conv_acc(r0, wk + 0, o);
  conv_acc(r1, wk + 3, o);
  conv_acc(r2, wk + 6, o);
#pragma unroll
  for (int c = 0; c < 8; ++c) o.v[c] = fminf(fmaxf(o.v[c], 0.0f), 1.0f);
  return o;
}

__device__ __forceinline__ F4 haarL1(const F8& e, const F8& o, float thr, float& acc) {
  F4 ll;
#pragma unroll
  for (int c = 0; c < 4; ++c) {
    const float a = e.v[2*c], b = e.v[2*c+1], cc = o.v[2*c], d = o.v[2*c+1];
    ll.v[c] = (a + b + cc + d) * 0.5f;
    const float lh = (a - b + cc - d) * 0.5f;
    const float hl = (a + b - cc - d) * 0.5f;
    const float hh = (a - b - cc + d) * 0.5f;
    acc += fminf(fabsf(lh), thr) + fminf(fabsf(hl), thr) + fminf(fabsf(hh), thr);
  }
  return ll;
}

__device__ __forceinline__ float haar1pair(float a, float b, float cc, float d,
                                           float thr, float& acc) {
  const float lh = (a - b + cc - d) * 0.5f;
  const float hl = (a + b - cc - d) * 0.5f;
  const float hh = (a - b - cc + d) * 0.5f;
  acc += fminf(fabsf(lh), thr) + fminf(fabsf(hl), thr) + fminf(fabsf(hh), thr);
  return (a + b + cc + d) * 0.5f;
}

__global__ __launch_bounds__(256, 2) void n2n_wavelet_kernel(
    const float* __restrict__ noisy,
    const float* __restrict__ weight,
    double* __restrict__ partial) {
  const int t = threadIdx.x;
  const int lane = t & 63;
  const int gwid = blockIdx.x * 4 + (t >> 6);
  const int strip = gwid & (NSTRIPS - 1);
  const int b = gwid >> 6;
  const float* base = noisy + (size_t)b * IMG * IMG + lane * 8;

  const int y0 = strip * S;
  const int k0 = y0 >> 1;                 // phase-row index of first pair
  const bool lastStrip = (y0 == IMG - S);

  // ---- Hoist ALL 24 dwordx4 loads: phase rows k0-1 .. k0+4 (clamped) ----
  float4 le0[6], le1[6], lo0[6], lo1[6];
#pragma unroll
  for (int i = 0; i < 6; ++i) {
    int r = k0 - 1 + i;
    r = r < 0 ? 0 : (r > 255 ? 255 : r);
    const float* pe = base + (2 * r) * IMG;       // even image row (p0 phase)
    const float* po = base + (2 * r + 1) * IMG;   // odd image row (p3 phase)
    le0[i] = *(const float4*)pe;
    le1[i] = *(const float4*)(pe + 4);
    lo0[i] = *(const float4*)po;
    lo1[i] = *(const float4*)(po + 4);
  }

  float wk[9];
#pragma unroll
  for (int i = 0; i < 9; ++i) wk[i] = weight[i];

  // ---- Extract checkerboard phases + horizontal blends (consume in order) ----
  F8 h0[6], h3[6];
#pragma unroll
  for (int i = 0; i < 6; ++i) {
    F4 e, o;
    e.v[0] = le0[i].x; e.v[1] = le0[i].z; e.v[2] = le1[i].x; e.v[3] = le1[i].z;
    o.v[0] = lo0[i].y; o.v[1] = lo0[i].w; o.v[2] = lo1[i].y; o.v[3] = lo1[i].w;
    h0[i] = hblend(e, lane);
    h3[i] = hblend(o, lane);
  }

  float rec = 0.f, rgg = 0.f, w1a = 0.f, w2a = 0.f, w3a = 0.f;
  const float thr1 = THR * 0.25f, thr2 = THR * 0.5f;

  // ---- g1 prologue rows y0-1 (odd), y0 (even) ----
  Row g1m, g1c;
  if (y0 == 0) {                                  // SAME conv zero-pad row -1
#pragma unroll
    for (int c = 0; c < 8; ++c) g1m.g.v[c] = 0.f;
    g1m.gl = 0.f; g1m.gr = 0.f;
  } else {
    g1m = vblend(h0[0], h0[1], 0.75f, 0.25f, lane);
  }
  g1c = vblend(h0[0], h0[1], 0.25f, 0.75f, lane);

  F4 ll1Prev;
  float ll2Prev0 = 0.f, ll2Prev1 = 0.f;

#pragma unroll
  for (int p = 0; p < 4; ++p) {
    const Row g1p = vblend(h0[p + 1], h0[p + 2], 0.75f, 0.25f, lane);  // g1[2k+1]

    // out row 2k (even)
    const F8 outE = conv3(g1m, g1c, g1p, wk);
#pragma unroll
    for (int c = 0; c < 8; ++c) {
      const float g2 = 0.25f * h3[p].v[c] + 0.75f * h3[p + 1].v[c];
      float d = outE.v[c] - g2;        rec += d*d;
      d = outE.v[c] - g1c.g.v[c];      rgg += d*d;
    }

    Row g1q = vblend(h0[p + 1], h0[p + 2], 0.25f, 0.75f, lane);        // g1[2k+2]
    if (lastStrip && p == 3) {                                         // g1[512]=0
#pragma unroll
      for (int c = 0; c < 8; ++c) g1q.g.v[c] = 0.f;
      g1q.gl = 0.f; g1q.gr = 0.f;
    }

    // out row 2k+1 (odd)
    const F8 outO = conv3(g1c, g1p, g1q, wk);
#pragma unroll
    for (int c = 0; c < 8; ++c) {
      const float g2 = 0.75f * h3[p + 1].v[c] + 0.25f * h3[p + 2].v[c];
      float d = outO.v[c] - g2;        rec += d*d;
      d = outO.v[c] - g1p.g.v[c];      rgg += d*d;
    }

    // Haar level 1 (rows 2k,2k+1; col pairs lane-local)
    const F4 ll1 = haarL1(outE, outO, thr1, w1a);
    if ((p & 1) == 0) {
      ll1Prev = ll1;
    } else {
      const float ll20 = haar1pair(ll1Prev.v[0], ll1Prev.v[1], ll1.v[0], ll1.v[1], thr2, w2a);
      const float ll21 = haar1pair(ll1Prev.v[2], ll1Prev.v[3], ll1.v[2], ll1.v[3], thr2, w2a);
      if (p == 1) {
        ll2Prev0 = ll20; ll2Prev1 = ll21;
      } else {
        const float lh = (ll2Prev0 - ll2Prev1 + ll20 - ll21) * 0.5f;
        const float hl = (ll2Prev0 + ll2Prev1 - ll20 - ll21) * 0.5f;
        const float hh = (ll2Prev0 - ll2Prev1 - ll20 + ll21) * 0.5f;
        w3a += fminf(fabsf(lh), THR) + fminf(fabsf(hl), THR) + fminf(fabsf(hh), THR);
      }
    }

    g1m = g1p; g1c = g1q;
  }

  // ---- Wave reduce -> one pre-weighted double per wave, plain store ----
  // (Separate finalize kernel on purpose: R6 showed per-block agent-scope
  //  release/acquire costs ~40 us of serialized L2 writeback/invalidate on
  //  MI355X. The kernel-launch boundary provides coherence for free.)
  float vals[5] = {rec, rgg, w1a, w2a, w3a};
#pragma unroll
  for (int v = 0; v < 5; ++v) {
#pragma unroll
    for (int off = 32; off > 0; off >>= 1) vals[v] += __shfl_down(vals[v], off);
  }
  if (lane == 0) {
    partial[gwid] = C_REC*(double)vals[0] + C_REG*(double)vals[1]
                  + C_W1*(double)vals[2] + C_W2*(double)vals[3] + C_W3*(double)vals[4];
  }
}

__global__ __launch_bounds__(256) void finalize_kernel(
    const double* __restrict__ partial, float* __restrict__ out) {
  __shared__ double sRed[4];
  const int t = threadIdx.x;
  double s = 0.0;
#pragma unroll
  for (int i = 0; i < NWAVES / 256; ++i) s += partial[i * 256 + t];
#pragma unroll
  for (int off = 32; off > 0; off >>= 1) s += __shfl_down(s, off);
  if ((t & 63) == 0) sRed[t >> 6] = s;
  __syncthreads();
  if (t == 0) out[0] = (float)(sRed[0] + sRed[1] + sRed[2] + sRed[3]);
}

}  // namespace

extern "C" void kernel_launch(void* const* d_in, const int* in_sizes, int n_in,
                              void* d_out, int out_size, void* d_ws, size_t ws_size,
                              hipStream_t stream) {
  const float* noisy  = (const float*)d_in[0];
  const float* weight = (const float*)d_in[1];
  double* partial = (double*)d_ws;   // NWAVES doubles = 16 KB
  float* out = (float*)d_out;

  hipLaunchKernelGGL(n2n_wavelet_kernel, dim3(NBLK), dim3(256), 0, stream,
                     noisy, weight, partial);
  hipLaunchKernelGGL(finalize_kernel, dim3(1), dim3(256), 0, stream, partial, out);
}